// Round 1
// baseline (910.983 us; speedup 1.0000x reference)
//
#include <hip/hip_runtime.h>
#include <stdint.h>

// CascadeAttention decode, MI355X (gfx950), fp32.
//
// R3: 2-dispatch cascade.
//  KA fused_kernel : 1280 blocks, 2:3 interleave of two paths.
//     l0 path (512 blocks = 64 chunk-groups x 8 h): stages 4 pages (64 tok)
//       of K/V h-slice into 64 KB LDS (XOR-swizzled), computes single-tile
//       partial attention for all 32 b. q comes from GLOBAL via wave-uniform
//       (readfirstlane) addresses -> scalar/K$ path, NOT the DS pipe (the
//       old q_lds broadcast was 41% of DS cycles). No inter-pass barriers.
//     seq path (768 blocks = b x h x 3 splits): as R2's seq_kernel, with q
//       read uniformly from global (b,h blockIdx-derived -> s_load).
//     64 KB LDS + VGPR<=128 (__launch_bounds__(512,4)) -> 2 blocks/CU,
//     16 waves/CU (was 1 block / 8 waves for l0).
//  KB merge_kernel : 256 blocks; exact LSE merge of 67 partials per (b,h,g).
// ws = 67 x [32][8][4][128] fp32 + m/l = ~35.7 MB. Fallback: proven R2
// single-kernel if ws too small.

namespace {
constexpr int kG = 4, kD = 128;
constexpr float kQS = 0.08838834764831845f * 1.4426950408889634f; // scale*log2e
constexpr int kNChunk = 64;   // L0: 64 groups x 4 pages
constexpr int kNSplit = 3;    // seq: 3 splits x 32 pages
constexpr int kNSrc = kNChunk + kNSplit;              // 67
constexpr size_t kOParts = (size_t)kNSrc * 32 * 8 * 4 * 128;   // o floats
constexpr size_t kMLB = kOParts;                               // m/l base
constexpr size_t kWsFloats = kOParts + (size_t)kNSrc * 32 * 8 * 4 * 2;
// kv strides (floats): page 32768, K->V 16384, token 1024, kvh 128
}

__device__ __forceinline__ float wave_max(float v) {
#pragma unroll
    for (int off = 1; off < 64; off <<= 1) v = fmaxf(v, __shfl_xor(v, off));
    return v;
}
__device__ __forceinline__ float wave_sum(float v) {
#pragma unroll
    for (int off = 1; off < 64; off <<= 1) v += __shfl_xor(v, off);
    return v;
}
// 16B-slot swizzles (32 slots per 128-float row) for conflict-free LDS.
__device__ __forceinline__ int kslot(int s, int t) { return s ^ (t & 31); }
__device__ __forceinline__ int vslot(int s, int t) {
    return s ^ (((t << 1) & 31) | ((t >> 4) & 1));
}

// ---------------- KA: fused l0 + seq partials ------------------------------
__global__ __launch_bounds__(512, 4)
void fused_kernel(const float* __restrict__ q, const float* __restrict__ kv,
                  const int* __restrict__ sp0, const int* __restrict__ sp1,
                  const int* __restrict__ sp2, float* __restrict__ ws)
{
    __shared__ __align__(16) float smem[16384];   // 64 KB union
    __shared__ int pgs[4];

    const int bid = blockIdx.x;
    const int grp = bid / 5, rem = bid % 5;       // 2:3 l0:seq interleave
    const int tid = threadIdx.x;
    const int w = tid >> 6, lane = tid & 63;
    const int ts = lane >> 4, dg = lane & 15;

    if (rem < 2) {
        // ================= L0 path: shared prefix, K/V-stationary ==========
        const int lid = grp * 2 + rem;            // 0..511
        const int h = lid & 7, c4 = lid >> 3;     // 64 groups x 8 h
        if (tid < 4) pgs[tid] = sp0[c4 * 4 + tid];
        __syncthreads();
        {   // stage 64 tokens of K and V (64 KB), swizzled; once per block
            const int t = tid >> 3;               // 0..63
            const int sg = (tid & 7) * 4;
            const int pg = pgs[t >> 4];
            const float* gk = kv + (size_t)pg * 32768u + (size_t)(t & 15) * 1024u + h * 128;
#pragma unroll
            for (int j = 0; j < 4; ++j) {
                const int s = sg + j;
                *(float4*)&smem[t * 128 + (kslot(s, t) << 2)] =
                    *(const float4*)(gk + s * 4);
                *(float4*)&smem[8192 + t * 128 + (vslot(s, t) << 2)] =
                    *(const float4*)(gk + 16384 + s * 4);
            }
        }
        __syncthreads();

        const int wq = __builtin_amdgcn_readfirstlane(w);
        for (int pass = 0; pass < 4; ++pass) {
            const int b = wq * 4 + pass;          // wave-uniform row batch
            const float* qb = q + (size_t)b * 4096 + h * 512;  // uniform addr
            float s[4] = {0.f, 0.f, 0.f, 0.f};
#pragma unroll
            for (int c = 0; c < 16; ++c) {
                float4 ka = *(const float4*)&smem[lane * 128 + (kslot(2 * c, lane) << 2)];
                float4 kb = *(const float4*)&smem[lane * 128 + (kslot(2 * c + 1, lane) << 2)];
#pragma unroll
                for (int g = 0; g < 4; ++g) {
                    float4 qa = *(const float4*)(qb + g * 128 + c * 8);
                    float4 q2 = *(const float4*)(qb + g * 128 + c * 8 + 4);
                    s[g] += ka.x * qa.x + ka.y * qa.y + ka.z * qa.z + ka.w * qa.w
                          + kb.x * q2.x + kb.y * q2.y + kb.z * q2.z + kb.w * q2.w;
                }
            }
            float m[4], p[4], l[4], acc[4][8];
#pragma unroll
            for (int g = 0; g < 4; ++g) {
                s[g] *= kQS;                      // scale post-dot (linear)
                m[g] = wave_max(s[g]);
                p[g] = exp2f(s[g] - m[g]);
                l[g] = wave_sum(p[g]);
#pragma unroll
                for (int e = 0; e < 8; ++e) acc[g][e] = 0.f;
            }
#pragma unroll
            for (int j = 0; j < 16; ++j) {
                const int t = ts * 16 + j;
                float4 va = *(const float4*)&smem[8192 + t * 128 + (vslot(2 * dg, t) << 2)];
                float4 vb = *(const float4*)&smem[8192 + t * 128 + (vslot(2 * dg + 1, t) << 2)];
#pragma unroll
                for (int g = 0; g < 4; ++g) {
                    float pj = __shfl(p[g], t);
                    acc[g][0] = fmaf(pj, va.x, acc[g][0]);
                    acc[g][1] = fmaf(pj, va.y, acc[g][1]);
                    acc[g][2] = fmaf(pj, va.z, acc[g][2]);
                    acc[g][3] = fmaf(pj, va.w, acc[g][3]);
                    acc[g][4] = fmaf(pj, vb.x, acc[g][4]);
                    acc[g][5] = fmaf(pj, vb.y, acc[g][5]);
                    acc[g][6] = fmaf(pj, vb.z, acc[g][6]);
                    acc[g][7] = fmaf(pj, vb.w, acc[g][7]);
                }
            }
            // reduce over 4 token-quarters; write partial (o, m, l); src = c4
#pragma unroll
            for (int g = 0; g < 4; ++g)
#pragma unroll
                for (int e = 0; e < 8; ++e) {
                    float v = acc[g][e];
                    v += __shfl_xor(v, 16);
                    v += __shfl_xor(v, 32);
                    acc[g][e] = v;
                }
            if (lane < 16) {
                const size_t ob = ((((size_t)c4 * 32 + b) * 8 + h) * 4) * 128 + lane * 8;
#pragma unroll
                for (int g = 0; g < 4; ++g) {
                    *(float4*)&ws[ob + (size_t)g * 128] =
                        make_float4(acc[g][0], acc[g][1], acc[g][2], acc[g][3]);
                    *(float4*)&ws[ob + (size_t)g * 128 + 4] =
                        make_float4(acc[g][4], acc[g][5], acc[g][6], acc[g][7]);
                }
            }
            if (lane == 0) {
                const size_t idx = (((size_t)c4 * 32 + b) * 8 + h) * 4;
#pragma unroll
                for (int g = 0; g < 4; ++g) {
                    ws[kMLB + 2 * (idx + g)] = m[g];
                    ws[kMLB + 2 * (idx + g) + 1] = l[g];
                }
            }
        }
    } else {
        // ================= seq path: per-sequence levels, split 3x =========
        const int sid = grp * 3 + (rem - 2);      // 0..767
        const int split = sid >> 8;
        const int b = (sid & 255) >> 3;
        const int h = sid & 7;
        float* wacc = smem;                       // [8][512]
        float* wm = smem + 4096;                  // [8][4]
        float* wl = smem + 4128;                  // [8][4]
        int* plist = (int*)(smem + 4160);         // [32]

        if (tid < 32) {
            const int gi = split * 32 + tid;
            plist[tid] = (gi < 64) ? sp1[b * 64 + gi] : sp2[b * 32 + (gi - 64)];
        }
        __syncthreads();

        const int page = plist[w * 4 + ts];
        const size_t poff = (size_t)page * 32768u;
        const float* Kp = kv + poff + (size_t)(lane & 15) * 1024u + h * 128;
        const float* Vp = kv + poff + 16384u + h * 128 + dg * 8;
        const float* qb = q + (size_t)b * 4096 + h * 512;  // uniform (blockIdx)

        float s[kG] = {0.f, 0.f, 0.f, 0.f};
#pragma unroll
        for (int c = 0; c < 16; ++c) {
            float4 ka = *(const float4*)(Kp + c * 8);
            float4 kb = *(const float4*)(Kp + c * 8 + 4);
#pragma unroll
            for (int g = 0; g < kG; ++g) {
                float4 qa = *(const float4*)(qb + g * 128 + c * 8);
                float4 q2 = *(const float4*)(qb + g * 128 + c * 8 + 4);
                s[g] += ka.x * qa.x + ka.y * qa.y + ka.z * qa.z + ka.w * qa.w
                      + kb.x * q2.x + kb.y * q2.y + kb.z * q2.z + kb.w * q2.w;
            }
        }
        float m[kG], p[kG], l[kG], acc[kG][8];
#pragma unroll
        for (int g = 0; g < kG; ++g) {
            s[g] *= kQS;
            m[g] = wave_max(s[g]);
            p[g] = exp2f(s[g] - m[g]);
            l[g] = wave_sum(p[g]);
#pragma unroll
            for (int e = 0; e < 8; ++e) acc[g][e] = 0.f;
        }
#pragma unroll
        for (int j = 0; j < 16; ++j) {
            const int t = ts * 16 + j;
            float4 va = *(const float4*)(Vp + (size_t)j * 1024u);
            float4 vb = *(const float4*)(Vp + (size_t)j * 1024u + 4);
#pragma unroll
            for (int g = 0; g < kG; ++g) {
                float pj = __shfl(p[g], t);
                acc[g][0] = fmaf(pj, va.x, acc[g][0]);
                acc[g][1] = fmaf(pj, va.y, acc[g][1]);
                acc[g][2] = fmaf(pj, va.z, acc[g][2]);
                acc[g][3] = fmaf(pj, va.w, acc[g][3]);
                acc[g][4] = fmaf(pj, vb.x, acc[g][4]);
                acc[g][5] = fmaf(pj, vb.y, acc[g][5]);
                acc[g][6] = fmaf(pj, vb.z, acc[g][6]);
                acc[g][7] = fmaf(pj, vb.w, acc[g][7]);
            }
        }
#pragma unroll
        for (int g = 0; g < kG; ++g)
#pragma unroll
            for (int e = 0; e < 8; ++e) {
                float v = acc[g][e];
                v += __shfl_xor(v, 16);
                v += __shfl_xor(v, 32);
                acc[g][e] = v;
            }
        if (lane < 16) {
#pragma unroll
            for (int g = 0; g < kG; ++g) {
                *(float4*)&wacc[w * 512 + g * 128 + dg * 8] =
                    make_float4(acc[g][0], acc[g][1], acc[g][2], acc[g][3]);
                *(float4*)&wacc[w * 512 + g * 128 + dg * 8 + 4] =
                    make_float4(acc[g][4], acc[g][5], acc[g][6], acc[g][7]);
            }
            if (lane == 0)
#pragma unroll
                for (int g = 0; g < kG; ++g) { wm[w * 4 + g] = m[g]; wl[w * 4 + g] = l[g]; }
        }
        __syncthreads();

        {   // block-level merge of 8 wave states -> one partial
            const int g = tid >> 7, d = tid & 127;
            float mstar = wm[g];
#pragma unroll
            for (int ww = 1; ww < 8; ++ww) mstar = fmaxf(mstar, wm[ww * 4 + g]);
            float numer = 0.f, denom = 0.f;
#pragma unroll
            for (int ww = 0; ww < 8; ++ww) {
                float sc = exp2f(wm[ww * 4 + g] - mstar);
                denom = fmaf(sc, wl[ww * 4 + g], denom);
                numer = fmaf(sc, wacc[ww * 512 + g * 128 + d], numer);
            }
            const size_t src = (size_t)(kNChunk + split);
            const size_t ob = (((src * 32 + b) * 8 + h) * 4 + g) * 128 + d;
            ws[ob] = numer;
            if (d == 0) {
                const size_t idx = ((src * 32 + b) * 8 + h) * 4 + g;
                ws[kMLB + 2 * idx] = mstar;
                ws[kMLB + 2 * idx + 1] = denom;
            }
        }
    }
}

// ---------------- KB: final merge of 67 partials ---------------------------
__global__ __launch_bounds__(512, 4)
void merge_kernel(const float* __restrict__ ws, float* __restrict__ out)
{
    __shared__ float sm[kNSrc][4], sl[kNSrc][4];
    const int b = blockIdx.x >> 3, h = blockIdx.x & 7;
    const int tid = threadIdx.x;
    if (tid < kNSrc * 4) {
        const int src = tid >> 2, g = tid & 3;
        const size_t idx = ((((size_t)src * 32 + b) * 8 + h) * 4 + g);
        sm[src][g] = ws[kMLB + 2 * idx];
        sl[src][g] = ws[kMLB + 2 * idx + 1];
    }
    __syncthreads();
    const int g = tid >> 7, d = tid & 127;
    float mstar = -1e30f;
#pragma unroll
    for (int s = 0; s < kNSrc; ++s) mstar = fmaxf(mstar, sm[s][g]);
    float numer = 0.f, denom = 0.f;
#pragma unroll 4
    for (int s = 0; s < kNSrc; ++s) {
        const float sc = exp2f(sm[s][g] - mstar);
        denom = fmaf(sc, sl[s][g], denom);
        const size_t ob = ((((size_t)s * 32 + b) * 8 + h) * 4 + g) * 128 + d;
        numer = fmaf(sc, ws[ob], numer);
    }
    out[(size_t)b * 4096 + h * 512 + g * 128 + d] = numer / denom;
}

// ---------------- fallback: proven R2 single kernel (fp32) -----------------
__global__ __launch_bounds__(512, 2)
void fallback_kernel(const float* __restrict__ q, const float* __restrict__ kv,
                     const int* __restrict__ sp0, const int* __restrict__ sp1,
                     const int* __restrict__ sp2, float* __restrict__ out)
{
    __shared__ __align__(16) float qs[kG * kD];
    __shared__ int plist[352];
    __shared__ __align__(16) float wacc[8][kG * kD];
    __shared__ float wm[8][kG], wl[8][kG];
    const int b = blockIdx.x >> 3, h = blockIdx.x & 7;
    const int tid = threadIdx.x;
    {
        const int g = tid >> 7, d = tid & 127;
        qs[g * 128 + d] = q[(size_t)b * 4096 + h * 512 + g * 128 + d] * kQS;
    }
    if (tid < 352) {
        int pg;
        if (tid < 256)      pg = sp0[tid];
        else if (tid < 320) pg = sp1[b * 64 + (tid - 256)];
        else                pg = sp2[b * 32 + (tid - 320)];
        plist[tid] = pg;
    }
    __syncthreads();
    const int w = tid >> 6, lane = tid & 63;
    const int ts = lane >> 4, dg = lane & 15;
    const float4* qv4 = (const float4*)qs;
    float m[kG], l[kG], acc[kG][8];
#pragma unroll
    for (int g = 0; g < kG; ++g) {
        m[g] = -1e30f; l[g] = 0.f;
#pragma unroll
        for (int e = 0; e < 8; ++e) acc[g][e] = 0.f;
    }
    for (int tile = 0; tile < 11; ++tile) {
        const int page = plist[w * 44 + tile * 4 + ts];
        const size_t poff = (size_t)page * 32768u;
        const float* Kp = kv + poff + (size_t)(lane & 15) * 1024u + h * 128;
        const float* Vp = kv + poff + 16384u + h * 128 + dg * 8;
        float s[kG] = {0.f, 0.f, 0.f, 0.f};
#pragma unroll
        for (int c = 0; c < 16; ++c) {
            float4 ka = *(const float4*)(Kp + c * 8);
            float4 kb = *(const float4*)(Kp + c * 8 + 4);
#pragma unroll
            for (int g = 0; g < kG; ++g) {
                float4 qa = qv4[g * 32 + c * 2];
                float4 qb = qv4[g * 32 + c * 2 + 1];
                s[g] += ka.x * qa.x + ka.y * qa.y + ka.z * qa.z + ka.w * qa.w
                      + kb.x * qb.x + kb.y * qb.y + kb.z * qb.z + kb.w * qb.w;
            }
        }
        float p[kG];
#pragma unroll
        for (int g = 0; g < kG; ++g) {
            float mt = wave_max(s[g]);
            float mn = fmaxf(m[g], mt);
            float alpha = exp2f(m[g] - mn);
            p[g] = exp2f(s[g] - mn);
            m[g] = mn;
            l[g] = l[g] * alpha + wave_sum(p[g]);
#pragma unroll
            for (int e = 0; e < 8; ++e) acc[g][e] *= alpha;
        }
#pragma unroll
        for (int j = 0; j < 16; ++j) {
            const int t = ts * 16 + j;
            float4 va = *(const float4*)(Vp + (size_t)j * 1024u);
            float4 vb = *(const float4*)(Vp + (size_t)j * 1024u + 4);
#pragma unroll
            for (int g = 0; g < kG; ++g) {
                float pj = __shfl(p[g], t);
                acc[g][0] = fmaf(pj, va.x, acc[g][0]);
                acc[g][1] = fmaf(pj, va.y, acc[g][1]);
                acc[g][2] = fmaf(pj, va.z, acc[g][2]);
                acc[g][3] = fmaf(pj, va.w, acc[g][3]);
                acc[g][4] = fmaf(pj, vb.x, acc[g][4]);
                acc[g][5] = fmaf(pj, vb.y, acc[g][5]);
                acc[g][6] = fmaf(pj, vb.z, acc[g][6]);
                acc[g][7] = fmaf(pj, vb.w, acc[g][7]);
            }
        }
    }
#pragma unroll
    for (int g = 0; g < kG; ++g)
#pragma unroll
        for (int e = 0; e < 8; ++e) {
            float v = acc[g][e];
            v += __shfl_xor(v, 16);
            v += __shfl_xor(v, 32);
            acc[g][e] = v;
        }
    if (lane < 16) {
#pragma unroll
        for (int g = 0; g < kG; ++g) {
            *(float4*)&wacc[w][g * 128 + dg * 8]     = make_float4(acc[g][0], acc[g][1], acc[g][2], acc[g][3]);
            *(float4*)&wacc[w][g * 128 + dg * 8 + 4] = make_float4(acc[g][4], acc[g][5], acc[g][6], acc[g][7]);
        }
        if (lane == 0)
#pragma unroll
            for (int g = 0; g < kG; ++g) { wm[w][g] = m[g]; wl[w][g] = l[g]; }
    }
    __syncthreads();
    {
        const int g = tid >> 7, d = tid & 127;
        float mstar = wm[0][g];
#pragma unroll
        for (int ww = 1; ww < 8; ++ww) mstar = fmaxf(mstar, wm[ww][g]);
        float numer = 0.f, denom = 0.f;
#pragma unroll
        for (int ww = 0; ww < 8; ++ww) {
            float sc = exp2f(wm[ww][g] - mstar);
            denom = fmaf(sc, wl[ww][g], denom);
            numer = fmaf(sc, wacc[ww][g * 128 + d], numer);
        }
        out[(size_t)b * 4096 + h * 512 + g * 128 + d] = numer / denom;
    }
}

extern "C" void kernel_launch(void* const* d_in, const int* in_sizes, int n_in,
                              void* d_out, int out_size, void* d_ws, size_t ws_size,
                              hipStream_t stream) {
    const float* q  = (const float*)d_in[0];
    const float* kv = (const float*)d_in[1];
    const int* sp0 = (const int*)d_in[2];
    const int* sp1 = (const int*)d_in[3];
    const int* sp2 = (const int*)d_in[4];
    float* out = (float*)d_out;
    float* ws = (float*)d_ws;
    if (ws_size >= kWsFloats * sizeof(float)) {
        hipLaunchKernelGGL(fused_kernel, dim3(1280), dim3(512), 0, stream,
                           q, kv, sp0, sp1, sp2, ws);
        hipLaunchKernelGGL(merge_kernel, dim3(256), dim3(512), 0, stream, ws, out);
    } else {
        hipLaunchKernelGGL(fallback_kernel, dim3(256), dim3(512), 0, stream,
                           q, kv, sp0, sp1, sp2, out);
    }
}

// Round 2
// 730.424 us; speedup vs baseline: 1.2472x; 1.2472x over previous
//
#include <hip/hip_runtime.h>
#include <stdint.h>

// CascadeAttention decode, MI355X (gfx950), fp32.
//
// R4: R3 structure with the spill fixed.
//  R3 post-mortem: __launch_bounds__(512,4) resolved to 8 waves/SIMD -> 64
//  VGPR cap -> massive scratch spill (FETCH +436 MB, WRITE +386 MB of pure
//  spill traffic, VALUBusy 8%). LDS (64.5 KB) already limits to 2 blocks/CU,
//  so the tighter reg cap bought nothing. R4 = identical kernel at
//  __launch_bounds__(512,2) (proven on R2's kernels; ~128 VGPR budget).
//
//  KA fused_kernel : 1280 blocks, 2:3 interleave of two paths.
//     l0 path (512 blocks = 64 chunk-groups x 8 h): stages 4 pages (64 tok)
//       of K/V h-slice into 64 KB LDS (XOR-swizzled), computes single-tile
//       partial attention for all 32 b. q comes from GLOBAL via wave-uniform
//       addresses -> scalar/K$ path, NOT the DS pipe.
//     seq path (768 blocks = b x h x 3 splits): one 4-page tile per wave,
//       single-tile softmax, block-level LSE merge -> partial.
//  KB merge_kernel : 256 blocks; exact LSE merge of 67 partials per (b,h,g).
// ws = 67 x [32][8][4][128] fp32 + m/l = ~35.7 MB. Fallback: proven R2
// single-kernel if ws too small.

namespace {
constexpr int kG = 4, kD = 128;
constexpr float kQS = 0.08838834764831845f * 1.4426950408889634f; // scale*log2e
constexpr int kNChunk = 64;   // L0: 64 groups x 4 pages
constexpr int kNSplit = 3;    // seq: 3 splits x 32 pages
constexpr int kNSrc = kNChunk + kNSplit;              // 67
constexpr size_t kOParts = (size_t)kNSrc * 32 * 8 * 4 * 128;   // o floats
constexpr size_t kMLB = kOParts;                               // m/l base
constexpr size_t kWsFloats = kOParts + (size_t)kNSrc * 32 * 8 * 4 * 2;
// kv strides (floats): page 32768, K->V 16384, token 1024, kvh 128
}

__device__ __forceinline__ float wave_max(float v) {
#pragma unroll
    for (int off = 1; off < 64; off <<= 1) v = fmaxf(v, __shfl_xor(v, off));
    return v;
}
__device__ __forceinline__ float wave_sum(float v) {
#pragma unroll
    for (int off = 1; off < 64; off <<= 1) v += __shfl_xor(v, off);
    return v;
}
// 16B-slot swizzles (32 slots per 128-float row) for conflict-free LDS.
__device__ __forceinline__ int kslot(int s, int t) { return s ^ (t & 31); }
__device__ __forceinline__ int vslot(int s, int t) {
    return s ^ (((t << 1) & 31) | ((t >> 4) & 1));
}

// ---------------- KA: fused l0 + seq partials ------------------------------
__global__ __launch_bounds__(512, 2)
void fused_kernel(const float* __restrict__ q, const float* __restrict__ kv,
                  const int* __restrict__ sp0, const int* __restrict__ sp1,
                  const int* __restrict__ sp2, float* __restrict__ ws)
{
    __shared__ __align__(16) float smem[16384];   // 64 KB union
    __shared__ int pgs[4];

    const int bid = blockIdx.x;
    const int grp = bid / 5, rem = bid % 5;       // 2:3 l0:seq interleave
    const int tid = threadIdx.x;
    const int w = tid >> 6, lane = tid & 63;
    const int ts = lane >> 4, dg = lane & 15;

    if (rem < 2) {
        // ================= L0 path: shared prefix, K/V-stationary ==========
        const int lid = grp * 2 + rem;            // 0..511
        const int h = lid & 7, c4 = lid >> 3;     // 64 groups x 8 h
        if (tid < 4) pgs[tid] = sp0[c4 * 4 + tid];
        __syncthreads();
        {   // stage 64 tokens of K and V (64 KB), swizzled; once per block
            const int t = tid >> 3;               // 0..63
            const int sg = (tid & 7) * 4;
            const int pg = pgs[t >> 4];
            const float* gk = kv + (size_t)pg * 32768u + (size_t)(t & 15) * 1024u + h * 128;
#pragma unroll
            for (int j = 0; j < 4; ++j) {
                const int s = sg + j;
                *(float4*)&smem[t * 128 + (kslot(s, t) << 2)] =
                    *(const float4*)(gk + s * 4);
                *(float4*)&smem[8192 + t * 128 + (vslot(s, t) << 2)] =
                    *(const float4*)(gk + 16384 + s * 4);
            }
        }
        __syncthreads();

        const int wq = __builtin_amdgcn_readfirstlane(w);
        for (int pass = 0; pass < 4; ++pass) {
            const int b = wq * 4 + pass;          // wave-uniform row batch
            const float* qb = q + (size_t)b * 4096 + h * 512;  // uniform addr
            float s[4] = {0.f, 0.f, 0.f, 0.f};
#pragma unroll
            for (int c = 0; c < 16; ++c) {
                float4 ka = *(const float4*)&smem[lane * 128 + (kslot(2 * c, lane) << 2)];
                float4 kb = *(const float4*)&smem[lane * 128 + (kslot(2 * c + 1, lane) << 2)];
#pragma unroll
                for (int g = 0; g < 4; ++g) {
                    float4 qa = *(const float4*)(qb + g * 128 + c * 8);
                    float4 q2 = *(const float4*)(qb + g * 128 + c * 8 + 4);
                    s[g] += ka.x * qa.x + ka.y * qa.y + ka.z * qa.z + ka.w * qa.w
                          + kb.x * q2.x + kb.y * q2.y + kb.z * q2.z + kb.w * q2.w;
                }
            }
            float m[4], p[4], l[4], acc[4][8];
#pragma unroll
            for (int g = 0; g < 4; ++g) {
                s[g] *= kQS;                      // scale post-dot (linear)
                m[g] = wave_max(s[g]);
                p[g] = exp2f(s[g] - m[g]);
                l[g] = wave_sum(p[g]);
#pragma unroll
                for (int e = 0; e < 8; ++e) acc[g][e] = 0.f;
            }
#pragma unroll
            for (int j = 0; j < 16; ++j) {
                const int t = ts * 16 + j;
                float4 va = *(const float4*)&smem[8192 + t * 128 + (vslot(2 * dg, t) << 2)];
                float4 vb = *(const float4*)&smem[8192 + t * 128 + (vslot(2 * dg + 1, t) << 2)];
#pragma unroll
                for (int g = 0; g < 4; ++g) {
                    float pj = __shfl(p[g], t);
                    acc[g][0] = fmaf(pj, va.x, acc[g][0]);
                    acc[g][1] = fmaf(pj, va.y, acc[g][1]);
                    acc[g][2] = fmaf(pj, va.z, acc[g][2]);
                    acc[g][3] = fmaf(pj, va.w, acc[g][3]);
                    acc[g][4] = fmaf(pj, vb.x, acc[g][4]);
                    acc[g][5] = fmaf(pj, vb.y, acc[g][5]);
                    acc[g][6] = fmaf(pj, vb.z, acc[g][6]);
                    acc[g][7] = fmaf(pj, vb.w, acc[g][7]);
                }
            }
            // reduce over 4 token-quarters; write partial (o, m, l); src = c4
#pragma unroll
            for (int g = 0; g < 4; ++g)
#pragma unroll
                for (int e = 0; e < 8; ++e) {
                    float v = acc[g][e];
                    v += __shfl_xor(v, 16);
                    v += __shfl_xor(v, 32);
                    acc[g][e] = v;
                }
            if (lane < 16) {
                const size_t ob = ((((size_t)c4 * 32 + b) * 8 + h) * 4) * 128 + lane * 8;
#pragma unroll
                for (int g = 0; g < 4; ++g) {
                    *(float4*)&ws[ob + (size_t)g * 128] =
                        make_float4(acc[g][0], acc[g][1], acc[g][2], acc[g][3]);
                    *(float4*)&ws[ob + (size_t)g * 128 + 4] =
                        make_float4(acc[g][4], acc[g][5], acc[g][6], acc[g][7]);
                }
            }
            if (lane == 0) {
                const size_t idx = (((size_t)c4 * 32 + b) * 8 + h) * 4;
#pragma unroll
                for (int g = 0; g < 4; ++g) {
                    ws[kMLB + 2 * (idx + g)] = m[g];
                    ws[kMLB + 2 * (idx + g) + 1] = l[g];
                }
            }
        }
    } else {
        // ================= seq path: per-sequence levels, split 3x =========
        const int sid = grp * 3 + (rem - 2);      // 0..767
        const int split = sid >> 8;
        const int b = (sid & 255) >> 3;
        const int h = sid & 7;
        float* wacc = smem;                       // [8][512]
        float* wm = smem + 4096;                  // [8][4]
        float* wl = smem + 4128;                  // [8][4]
        int* plist = (int*)(smem + 4160);         // [32]

        if (tid < 32) {
            const int gi = split * 32 + tid;
            plist[tid] = (gi < 64) ? sp1[b * 64 + gi] : sp2[b * 32 + (gi - 64)];
        }
        __syncthreads();

        const int page = plist[w * 4 + ts];
        const size_t poff = (size_t)page * 32768u;
        const float* Kp = kv + poff + (size_t)(lane & 15) * 1024u + h * 128;
        const float* Vp = kv + poff + 16384u + h * 128 + dg * 8;
        const float* qb = q + (size_t)b * 4096 + h * 512;  // uniform (blockIdx)

        float s[kG] = {0.f, 0.f, 0.f, 0.f};
#pragma unroll
        for (int c = 0; c < 16; ++c) {
            float4 ka = *(const float4*)(Kp + c * 8);
            float4 kb = *(const float4*)(Kp + c * 8 + 4);
#pragma unroll
            for (int g = 0; g < kG; ++g) {
                float4 qa = *(const float4*)(qb + g * 128 + c * 8);
                float4 q2 = *(const float4*)(qb + g * 128 + c * 8 + 4);
                s[g] += ka.x * qa.x + ka.y * qa.y + ka.z * qa.z + ka.w * qa.w
                      + kb.x * q2.x + kb.y * q2.y + kb.z * q2.z + kb.w * q2.w;
            }
        }
        float m[kG], p[kG], l[kG], acc[kG][8];
#pragma unroll
        for (int g = 0; g < kG; ++g) {
            s[g] *= kQS;
            m[g] = wave_max(s[g]);
            p[g] = exp2f(s[g] - m[g]);
            l[g] = wave_sum(p[g]);
#pragma unroll
            for (int e = 0; e < 8; ++e) acc[g][e] = 0.f;
        }
#pragma unroll
        for (int j = 0; j < 16; ++j) {
            const int t = ts * 16 + j;
            float4 va = *(const float4*)(Vp + (size_t)j * 1024u);
            float4 vb = *(const float4*)(Vp + (size_t)j * 1024u + 4);
#pragma unroll
            for (int g = 0; g < kG; ++g) {
                float pj = __shfl(p[g], t);
                acc[g][0] = fmaf(pj, va.x, acc[g][0]);
                acc[g][1] = fmaf(pj, va.y, acc[g][1]);
                acc[g][2] = fmaf(pj, va.z, acc[g][2]);
                acc[g][3] = fmaf(pj, va.w, acc[g][3]);
                acc[g][4] = fmaf(pj, vb.x, acc[g][4]);
                acc[g][5] = fmaf(pj, vb.y, acc[g][5]);
                acc[g][6] = fmaf(pj, vb.z, acc[g][6]);
                acc[g][7] = fmaf(pj, vb.w, acc[g][7]);
            }
        }
#pragma unroll
        for (int g = 0; g < kG; ++g)
#pragma unroll
            for (int e = 0; e < 8; ++e) {
                float v = acc[g][e];
                v += __shfl_xor(v, 16);
                v += __shfl_xor(v, 32);
                acc[g][e] = v;
            }
        if (lane < 16) {
#pragma unroll
            for (int g = 0; g < kG; ++g) {
                *(float4*)&wacc[w * 512 + g * 128 + dg * 8] =
                    make_float4(acc[g][0], acc[g][1], acc[g][2], acc[g][3]);
                *(float4*)&wacc[w * 512 + g * 128 + dg * 8 + 4] =
                    make_float4(acc[g][4], acc[g][5], acc[g][6], acc[g][7]);
            }
            if (lane == 0)
#pragma unroll
                for (int g = 0; g < kG; ++g) { wm[w * 4 + g] = m[g]; wl[w * 4 + g] = l[g]; }
        }
        __syncthreads();

        {   // block-level merge of 8 wave states -> one partial
            const int g = tid >> 7, d = tid & 127;
            float mstar = wm[g];
#pragma unroll
            for (int ww = 1; ww < 8; ++ww) mstar = fmaxf(mstar, wm[ww * 4 + g]);
            float numer = 0.f, denom = 0.f;
#pragma unroll
            for (int ww = 0; ww < 8; ++ww) {
                float sc = exp2f(wm[ww * 4 + g] - mstar);
                denom = fmaf(sc, wl[ww * 4 + g], denom);
                numer = fmaf(sc, wacc[ww * 512 + g * 128 + d], numer);
            }
            const size_t src = (size_t)(kNChunk + split);
            const size_t ob = (((src * 32 + b) * 8 + h) * 4 + g) * 128 + d;
            ws[ob] = numer;
            if (d == 0) {
                const size_t idx = ((src * 32 + b) * 8 + h) * 4 + g;
                ws[kMLB + 2 * idx] = mstar;
                ws[kMLB + 2 * idx + 1] = denom;
            }
        }
    }
}

// ---------------- KB: final merge of 67 partials ---------------------------
__global__ __launch_bounds__(512, 4)
void merge_kernel(const float* __restrict__ ws, float* __restrict__ out)
{
    __shared__ float sm[kNSrc][4], sl[kNSrc][4];
    const int b = blockIdx.x >> 3, h = blockIdx.x & 7;
    const int tid = threadIdx.x;
    if (tid < kNSrc * 4) {
        const int src = tid >> 2, g = tid & 3;
        const size_t idx = ((((size_t)src * 32 + b) * 8 + h) * 4 + g);
        sm[src][g] = ws[kMLB + 2 * idx];
        sl[src][g] = ws[kMLB + 2 * idx + 1];
    }
    __syncthreads();
    const int g = tid >> 7, d = tid & 127;
    float mstar = -1e30f;
#pragma unroll
    for (int s = 0; s < kNSrc; ++s) mstar = fmaxf(mstar, sm[s][g]);
    float numer = 0.f, denom = 0.f;
#pragma unroll 4
    for (int s = 0; s < kNSrc; ++s) {
        const float sc = exp2f(sm[s][g] - mstar);
        denom = fmaf(sc, sl[s][g], denom);
        const size_t ob = ((((size_t)s * 32 + b) * 8 + h) * 4 + g) * 128 + d;
        numer = fmaf(sc, ws[ob], numer);
    }
    out[(size_t)b * 4096 + h * 512 + g * 128 + d] = numer / denom;
}

// ---------------- fallback: proven R2 single kernel (fp32) -----------------
__global__ __launch_bounds__(512, 2)
void fallback_kernel(const float* __restrict__ q, const float* __restrict__ kv,
                     const int* __restrict__ sp0, const int* __restrict__ sp1,
                     const int* __restrict__ sp2, float* __restrict__ out)
{
    __shared__ __align__(16) float qs[kG * kD];
    __shared__ int plist[352];
    __shared__ __align__(16) float wacc[8][kG * kD];
    __shared__ float wm[8][kG], wl[8][kG];
    const int b = blockIdx.x >> 3, h = blockIdx.x & 7;
    const int tid = threadIdx.x;
    {
        const int g = tid >> 7, d = tid & 127;
        qs[g * 128 + d] = q[(size_t)b * 4096 + h * 512 + g * 128 + d] * kQS;
    }
    if (tid < 352) {
        int pg;
        if (tid < 256)      pg = sp0[tid];
        else if (tid < 320) pg = sp1[b * 64 + (tid - 256)];
        else                pg = sp2[b * 32 + (tid - 320)];
        plist[tid] = pg;
    }
    __syncthreads();
    const int w = tid >> 6, lane = tid & 63;
    const int ts = lane >> 4, dg = lane & 15;
    const float4* qv4 = (const float4*)qs;
    float m[kG], l[kG], acc[kG][8];
#pragma unroll
    for (int g = 0; g < kG; ++g) {
        m[g] = -1e30f; l[g] = 0.f;
#pragma unroll
        for (int e = 0; e < 8; ++e) acc[g][e] = 0.f;
    }
    for (int tile = 0; tile < 11; ++tile) {
        const int page = plist[w * 44 + tile * 4 + ts];
        const size_t poff = (size_t)page * 32768u;
        const float* Kp = kv + poff + (size_t)(lane & 15) * 1024u + h * 128;
        const float* Vp = kv + poff + 16384u + h * 128 + dg * 8;
        float s[kG] = {0.f, 0.f, 0.f, 0.f};
#pragma unroll
        for (int c = 0; c < 16; ++c) {
            float4 ka = *(const float4*)(Kp + c * 8);
            float4 kb = *(const float4*)(Kp + c * 8 + 4);
#pragma unroll
            for (int g = 0; g < kG; ++g) {
                float4 qa = qv4[g * 32 + c * 2];
                float4 qb = qv4[g * 32 + c * 2 + 1];
                s[g] += ka.x * qa.x + ka.y * qa.y + ka.z * qa.z + ka.w * qa.w
                      + kb.x * qb.x + kb.y * qb.y + kb.z * qb.z + kb.w * qb.w;
            }
        }
        float p[kG];
#pragma unroll
        for (int g = 0; g < kG; ++g) {
            float mt = wave_max(s[g]);
            float mn = fmaxf(m[g], mt);
            float alpha = exp2f(m[g] - mn);
            p[g] = exp2f(s[g] - mn);
            m[g] = mn;
            l[g] = l[g] * alpha + wave_sum(p[g]);
#pragma unroll
            for (int e = 0; e < 8; ++e) acc[g][e] *= alpha;
        }
#pragma unroll
        for (int j = 0; j < 16; ++j) {
            const int t = ts * 16 + j;
            float4 va = *(const float4*)(Vp + (size_t)j * 1024u);
            float4 vb = *(const float4*)(Vp + (size_t)j * 1024u + 4);
#pragma unroll
            for (int g = 0; g < kG; ++g) {
                float pj = __shfl(p[g], t);
                acc[g][0] = fmaf(pj, va.x, acc[g][0]);
                acc[g][1] = fmaf(pj, va.y, acc[g][1]);
                acc[g][2] = fmaf(pj, va.z, acc[g][2]);
                acc[g][3] = fmaf(pj, va.w, acc[g][3]);
                acc[g][4] = fmaf(pj, vb.x, acc[g][4]);
                acc[g][5] = fmaf(pj, vb.y, acc[g][5]);
                acc[g][6] = fmaf(pj, vb.z, acc[g][6]);
                acc[g][7] = fmaf(pj, vb.w, acc[g][7]);
            }
        }
    }
#pragma unroll
    for (int g = 0; g < kG; ++g)
#pragma unroll
        for (int e = 0; e < 8; ++e) {
            float v = acc[g][e];
            v += __shfl_xor(v, 16);
            v += __shfl_xor(v, 32);
            acc[g][e] = v;
        }
    if (lane < 16) {
#pragma unroll
        for (int g = 0; g < kG; ++g) {
            *(float4*)&wacc[w][g * 128 + dg * 8]     = make_float4(acc[g][0], acc[g][1], acc[g][2], acc[g][3]);
            *(float4*)&wacc[w][g * 128 + dg * 8 + 4] = make_float4(acc[g][4], acc[g][5], acc[g][6], acc[g][7]);
        }
        if (lane == 0)
#pragma unroll
            for (int g = 0; g < kG; ++g) { wm[w][g] = m[g]; wl[w][g] = l[g]; }
    }
    __syncthreads();
    {
        const int g = tid >> 7, d = tid & 127;
        float mstar = wm[0][g];
#pragma unroll
        for (int ww = 1; ww < 8; ++ww) mstar = fmaxf(mstar, wm[ww][g]);
        float numer = 0.f, denom = 0.f;
#pragma unroll
        for (int ww = 0; ww < 8; ++ww) {
            float sc = exp2f(wm[ww][g] - mstar);
            denom = fmaf(sc, wl[ww][g], denom);
            numer = fmaf(sc, wacc[ww][g * 128 + d], numer);
        }
        out[(size_t)b * 4096 + h * 512 + g * 128 + d] = numer / denom;
    }
}

extern "C" void kernel_launch(void* const* d_in, const int* in_sizes, int n_in,
                              void* d_out, int out_size, void* d_ws, size_t ws_size,
                              hipStream_t stream) {
    const float* q  = (const float*)d_in[0];
    const float* kv = (const float*)d_in[1];
    const int* sp0 = (const int*)d_in[2];
    const int* sp1 = (const int*)d_in[3];
    const int* sp2 = (const int*)d_in[4];
    float* out = (float*)d_out;
    float* ws = (float*)d_ws;
    if (ws_size >= kWsFloats * sizeof(float)) {
        hipLaunchKernelGGL(fused_kernel, dim3(1280), dim3(512), 0, stream,
                           q, kv, sp0, sp1, sp2, ws);
        hipLaunchKernelGGL(merge_kernel, dim3(256), dim3(512), 0, stream, ws, out);
    } else {
        hipLaunchKernelGGL(fallback_kernel, dim3(256), dim3(512), 0, stream,
                           q, kv, sp0, sp1, sp2, out);
    }
}